// Round 11
// baseline (232.573 us; speedup 1.0000x reference)
//
#include <hip/hip_runtime.h>

#define FDIM  256
#define H1D   256
#define H2D   128
#define BATCH 4096
#define NPART 64

typedef _Float16 half8 __attribute__((ext_vector_type(8)));
typedef float    f32x4 __attribute__((ext_vector_type(4)));

#define W2F_HALVES  ((size_t)FDIM * H1D * H2D)   // 8388608  (16.78 MB)
#define XH_HALVES   ((size_t)FDIM * BATCH)       // 1048576  (2 MB)
#define W1B1_HALVES ((size_t)FDIM * 8 * 4 * 16)  // 131072   (0.25 MB)

// ---------------------------------------------------------------------------
// prep_all: three independent jobs branched on blockIdx.
//  [0,2048):   W2 (f32) -> w2f f16 B-fragments, k-perm kpat(g,j)=4g+j / 16+4g+(j-4)
//  [2048,2304): x (B,F) f32 -> xh (F,B) f16 transpose via LDS tile
//  [2304,2336): W1,b1 -> w1b1 f16 packed per (f,s,g): 8 W1 halves + 8 b1 halves,
//               SAME kpat sigma as w2f (A/B K-map consistency).
// ---------------------------------------------------------------------------
__global__ __launch_bounds__(256) void prep_all(
    const float* __restrict__ x,  const float* __restrict__ W1,
    const float* __restrict__ b1, const float* __restrict__ W2,
    _Float16* __restrict__ w2f, _Float16* __restrict__ xh,
    _Float16* __restrict__ w1b1) {
    __shared__ _Float16 tile[64][66];
    const int tid = threadIdx.x;
    const int bid = blockIdx.x;
    if (bid < 2048) {
        const int f = bid >> 3, s = bid & 7;
        const int lane = tid & 63, g = lane >> 4, ln = lane & 15;
        const int w = tid >> 6;
#pragma unroll
        for (int h = 0; h < 2; ++h) {
            const int tq = w * 2 + h;
            half8 v;
#pragma unroll
            for (int j = 0; j < 8; ++j) {
                const int k = s * 32 + 4 * g + (j < 4 ? j : 12 + j);
                v[j] = (_Float16)W2[(size_t)(f * H1D + k) * H2D + tq * 16 + ln];
            }
            *(half8*)(w2f + (((size_t)(f * 8 + s) * 8 + tq) * 64 + lane) * 8) = v;
        }
    } else if (bid < 2304) {
        const int idx = bid - 2048;
        const int bt = idx >> 2, ft = idx & 3;
        const int tr = tid >> 2;          // 0..63: batch row within tile
        const int c0 = (tid & 3) * 16;    // feature col chunk
#pragma unroll
        for (int j = 0; j < 4; ++j) {
            const float4 v = *(const float4*)(
                x + (size_t)(bt * 64 + tr) * FDIM + ft * 64 + c0 + j * 4);
            tile[tr][c0 + j * 4 + 0] = (_Float16)v.x;
            tile[tr][c0 + j * 4 + 1] = (_Float16)v.y;
            tile[tr][c0 + j * 4 + 2] = (_Float16)v.z;
            tile[tr][c0 + j * 4 + 3] = (_Float16)v.w;
        }
        __syncthreads();
        const int fr = tid >> 2;          // feature row 0..63
        const int bb = (tid & 3) * 16;    // batch chunk
        half8 o0, o1;
#pragma unroll
        for (int i = 0; i < 8; ++i) o0[i] = tile[bb + i][fr];
#pragma unroll
        for (int i = 0; i < 8; ++i) o1[i] = tile[bb + 8 + i][fr];
        _Float16* dst = xh + (size_t)(ft * 64 + fr) * BATCH + bt * 64 + bb;
        *(half8*)dst = o0;
        *(half8*)(dst + 8) = o1;
    } else {
        const int idx = (bid - 2304) * 256 + tid;   // 0..8191
        const int f = idx >> 5, s = (idx >> 2) & 7, g = idx & 3;
        const float4 wlo = *(const float4*)(W1 + f * H1D + s * 32 + 4 * g);
        const float4 whi = *(const float4*)(W1 + f * H1D + s * 32 + 16 + 4 * g);
        const float4 blo = *(const float4*)(b1 + f * H1D + s * 32 + 4 * g);
        const float4 bhi = *(const float4*)(b1 + f * H1D + s * 32 + 16 + 4 * g);
        half8 wv, bv;
        wv[0] = (_Float16)wlo.x; wv[1] = (_Float16)wlo.y;
        wv[2] = (_Float16)wlo.z; wv[3] = (_Float16)wlo.w;
        wv[4] = (_Float16)whi.x; wv[5] = (_Float16)whi.y;
        wv[6] = (_Float16)whi.z; wv[7] = (_Float16)whi.w;
        bv[0] = (_Float16)blo.x; bv[1] = (_Float16)blo.y;
        bv[2] = (_Float16)blo.z; bv[3] = (_Float16)blo.w;
        bv[4] = (_Float16)bhi.x; bv[5] = (_Float16)bhi.y;
        bv[6] = (_Float16)bhi.z; bv[7] = (_Float16)bhi.w;
        _Float16* dst = w1b1 + (size_t)((f * 8 + s) * 4 + g) * 16;
        *(half8*)dst = wv;
        *(half8*)(dst + 8) = bv;
    }
}

// ---------------------------------------------------------------------------
// Main: 1024 blocks (EXACTLY 4/CU) x 4 waves = 4 waves/SIMD, one residency
// round. Wave = 64 rows x 64 cols x 8 features. Register-dieted to fit
// 4 waves (launch_bounds(256,4), ~128 unified regs): acc 64 AGPR,
// BK=32 B-frag ring 32 VGPR, wvb/bvb ring 16, transient b2v/w3v, xs
// reloaded per feature, 32-bit running offsets. The 4 waves/SIMD overlap
// each other's VALU<->MFMA dependency chains (both pipes need ~33 us
// aggregate -> target max(), not sum). Barrier-free, LDS-free; setprio
// wraps the MFMA cluster.
// ---------------------------------------------------------------------------
__global__ __launch_bounds__(256, 4) void coxnam_main(
    const _Float16* __restrict__ xh,  const _Float16* __restrict__ w1b1,
    const _Float16* __restrict__ w2f, const float* __restrict__ b2,
    const float* __restrict__ W3,     float* __restrict__ partial) {
    const int t    = threadIdx.x;
    const int w    = t >> 6;
    const int lane = t & 63;
    const int g = lane >> 4, ln = lane & 15;
    const int bid = blockIdx.x;                 // 0..1023
    const int xcd = bid & 7;
    const int r_  = bid >> 3;                   // 0..127
    const int fsplit = (xcd << 2) | (r_ & 3);   // 0..31 (8 features each)
    const int u   = r_ >> 2;                    // 0..31
    const int ns  = u & 1, btg = u >> 1;        // btg 0..15
    const int b0  = (btg * 4 + w) * 64;         // 64 rows per wave
    const int n0  = ns * 64, f0 = fsplit * 8;

    f32x4 acc[4][4];                 // 64 AGPR
    float sacc[4][4];
    half8 bfb[2][4];                 // BK=32 double-buffer: 32 VGPR
    half8 wvb[2], bvb[2];            // 16 VGPR
    _Float16 xs[4];
#pragma unroll
    for (int mi = 0; mi < 4; ++mi)
#pragma unroll
        for (int r = 0; r < 4; ++r) sacc[mi][r] = 0.f;

    // 32-bit running offsets (element units) off SGPR bases
    int off_b = f0 * 32768 + ns * 2048 + lane * 8;  // w2f, +4096/chunk
    int off_w = f0 * 512 + g * 16;                  // w1b1, +64/chunk
    int off_x = f0 * BATCH + b0 + ln;               // xh,   +BATCH/feature
    int off_e = f0 * H2D + n0 + ln;                 // b2/W3, +H2D/feature

    // prologue: chunk 0 -> ring 0
#pragma unroll
    for (int nt = 0; nt < 4; ++nt)
        bfb[0][nt] = *(const half8*)(w2f + off_b + nt * 512);
    wvb[0] = *(const half8*)(w1b1 + off_w);
    bvb[0] = *(const half8*)(w1b1 + off_w + 8);
    off_b += 4096;
    off_w += 64;

    for (int fi = 0; fi < 8; ++fi) {
        // transient b2 -> acc init; xs reload (L1/L2-hot, covered by 4 waves)
        {
            float b2v[4];
#pragma unroll
            for (int nt = 0; nt < 4; ++nt) b2v[nt] = b2[off_e + nt * 16];
#pragma unroll
            for (int mi = 0; mi < 4; ++mi)
#pragma unroll
                for (int nt = 0; nt < 4; ++nt)
                    acc[mi][nt] = (f32x4){b2v[nt], b2v[nt], b2v[nt], b2v[nt]};
        }
#pragma unroll
        for (int mi = 0; mi < 4; ++mi) xs[mi] = xh[off_x + mi * 16];
#pragma unroll
        for (int s = 0; s < 8; ++s) {
            const int cur = s & 1, nxt = cur ^ 1;   // compile-time (unrolled)
            // prefetch next chunk (ring): valid while chunks remain
            if (s < 7 || fi < 7) {
#pragma unroll
                for (int nt = 0; nt < 4; ++nt)
                    bfb[nxt][nt] = *(const half8*)(w2f + off_b + nt * 512);
                wvb[nxt] = *(const half8*)(w1b1 + off_w);
                bvb[nxt] = *(const half8*)(w1b1 + off_w + 8);
            }
            off_b += 4096;
            off_w += 64;
            // A-frag recompute (packed f16) + 16-MFMA cluster
            __builtin_amdgcn_s_setprio(1);
#pragma unroll
            for (int mi = 0; mi < 4; ++mi) {
                const half8 tt = xs[mi] * wvb[cur] + bvb[cur];
                const half8 af =
                    __builtin_elementwise_max(tt, (half8)(_Float16)0.0f);
#pragma unroll
                for (int nt = 0; nt < 4; ++nt)
                    acc[mi][nt] = __builtin_amdgcn_mfma_f32_16x16x32_f16(
                        af, bfb[cur][nt], acc[mi][nt], 0, 0, 0);
            }
            __builtin_amdgcn_s_setprio(0);
        }
        // ---- epilogue: relu(acc) . W3 -> sacc (b2 already inside acc) ----
        {
            float w3v[4];
#pragma unroll
            for (int nt = 0; nt < 4; ++nt) w3v[nt] = W3[off_e + nt * 16];
#pragma unroll
            for (int mi = 0; mi < 4; ++mi)
#pragma unroll
                for (int nt = 0; nt < 4; ++nt)
#pragma unroll
                    for (int r = 0; r < 4; ++r) {
                        const float v = fmaxf(acc[mi][nt][r], 0.f);
                        sacc[mi][r] = fmaf(v, w3v[nt], sacc[mi][r]);
                    }
        }
        off_x += BATCH;
        off_e += H2D;
    }

    // ---- reduce over the 16 n-lanes ----
#pragma unroll
    for (int mi = 0; mi < 4; ++mi)
#pragma unroll
        for (int r = 0; r < 4; ++r) {
            float v = sacc[mi][r];
            v += __shfl_xor(v, 1, 16);
            v += __shfl_xor(v, 2, 16);
            v += __shfl_xor(v, 4, 16);
            v += __shfl_xor(v, 8, 16);
            sacc[mi][r] = v;
        }
    if (ln == 0) {
        float* dst = partial + (size_t)(fsplit * 2 + ns) * BATCH + b0;
#pragma unroll
        for (int mi = 0; mi < 4; ++mi) {
            f32x4 o = {sacc[mi][0], sacc[mi][1], sacc[mi][2], sacc[mi][3]};
            *(f32x4*)(dst + mi * 16 + g * 4) = o;
        }
    }
}

// ---------------------------------------------------------------------------
// Final reduction over 64 partials + sum of b3.
// ---------------------------------------------------------------------------
__global__ __launch_bounds__(256) void reduce_out(const float* __restrict__ partial,
                                                  const float* __restrict__ b3,
                                                  float* __restrict__ out) {
    const int b = blockIdx.x * 256 + threadIdx.x;
    float v = 0.f;
#pragma unroll
    for (int p = 0; p < NPART; ++p) v += partial[(size_t)p * BATCH + b];
    float sb3 = 0.f;
#pragma unroll 4
    for (int f4 = 0; f4 < FDIM; f4 += 4) {
        const float4 t = *(const float4*)(b3 + f4);
        sb3 += t.x + t.y + t.z + t.w;
    }
    out[b] = v + sb3;
}

extern "C" void kernel_launch(void* const* d_in, const int* in_sizes, int n_in,
                              void* d_out, int out_size, void* d_ws, size_t ws_size,
                              hipStream_t stream) {
    const float* x  = (const float*)d_in[0];
    const float* W1 = (const float*)d_in[1];
    const float* b1 = (const float*)d_in[2];
    const float* W2 = (const float*)d_in[3];
    const float* b2 = (const float*)d_in[4];
    const float* W3 = (const float*)d_in[5];
    const float* b3 = (const float*)d_in[6];

    _Float16* w2f  = (_Float16*)d_ws;
    _Float16* xh   = w2f + W2F_HALVES;
    _Float16* w1b1 = xh + XH_HALVES;
    float* partial = (float*)(w1b1 + W1B1_HALVES);
    const size_t need = (W2F_HALVES + XH_HALVES + W1B1_HALVES) * sizeof(_Float16) +
                        (size_t)NPART * BATCH * sizeof(float);
    if (ws_size < need) return;  // insufficient scratch; fail visibly

    prep_all<<<2336, 256, 0, stream>>>(x, W1, b1, W2, w2f, xh, w1b1);
    coxnam_main<<<1024, 256, 0, stream>>>(xh, w1b1, w2f, b2, W3, partial);
    reduce_out<<<BATCH / 256, 256, 0, stream>>>(partial, b3, (float*)d_out);
}

// Round 12
// 151.265 us; speedup vs baseline: 1.5375x; 1.5375x over previous
//
#include <hip/hip_runtime.h>

#define FDIM  256
#define H1D   256
#define H2D   128
#define BATCH 4096
#define NPART 32

typedef _Float16 half8  __attribute__((ext_vector_type(8)));
typedef float    f32x16 __attribute__((ext_vector_type(16)));

#define W2F_HALVES  ((size_t)FDIM * H1D * H2D)   // 8388608  (16.78 MB)
#define XH_HALVES   ((size_t)FDIM * BATCH)       // 1048576  (2 MB)
#define W1B1_HALVES ((size_t)FDIM * 16 * 32)     // 131072   (0.25 MB)

// K-map for 32x32x16 operands (half h = lane>>5, j = 0..7):
// kp32(h,j) = 4h+j (j<4) | 8+4h+(j-4) (j>=4).  Used IDENTICALLY for the
// in-register A recompute and the w2f/w1b1 prep layouts (sigma-consistency:
// any true HW K-permutation cancels in the product).
__device__ __forceinline__ int kp32(int h, int j) {
    return j < 4 ? 4 * h + j : 8 + 4 * h + (j - 4);
}

// ---------------------------------------------------------------------------
// prep_all:
//  [0,4096):    (f,s) -> w2f f16 B-fragments for 32x32x16.
//               block = (f = bid>>4, s = bid&15); thread (nt = tid>>6, lane):
//               elem j: W2[f][16s + kp32(l>>5,j)][32nt + (l&31)]
//               -> w2f[((f*16+s)*4+nt)*512 + lane*8 + j]
//  [4096,4352): x (B,F) f32 -> xh (F,B) f16 transpose via LDS tile
//  [4352,4384): W1,b1 -> w1b1: per (f,s) 32 halves: [h*8+j]=W1[f][16s+kp32(h,j)],
//               [16+h*8+j]=b1 same map.
// ---------------------------------------------------------------------------
__global__ __launch_bounds__(256) void prep_all(
    const float* __restrict__ x,  const float* __restrict__ W1,
    const float* __restrict__ b1, const float* __restrict__ W2,
    _Float16* __restrict__ w2f, _Float16* __restrict__ xh,
    _Float16* __restrict__ w1b1) {
    __shared__ _Float16 tile[64][66];
    const int tid = threadIdx.x;
    const int bid = blockIdx.x;
    if (bid < 4096) {
        const int f = bid >> 4, s = bid & 15;
        const int nt = tid >> 6, lane = tid & 63;
        const int h = lane >> 5, c = lane & 31;
        half8 v;
#pragma unroll
        for (int j = 0; j < 8; ++j) {
            const int k = 16 * s + kp32(h, j);
            v[j] = (_Float16)W2[(size_t)(f * H1D + k) * H2D + nt * 32 + c];
        }
        *(half8*)(w2f + (((size_t)(f * 16 + s) * 4 + nt) * 64 + lane) * 8) = v;
    } else if (bid < 4352) {
        const int idx = bid - 4096;
        const int bt = idx >> 2, ft = idx & 3;
        const int tr = tid >> 2;
        const int c0 = (tid & 3) * 16;
#pragma unroll
        for (int j = 0; j < 4; ++j) {
            const float4 v = *(const float4*)(
                x + (size_t)(bt * 64 + tr) * FDIM + ft * 64 + c0 + j * 4);
            tile[tr][c0 + j * 4 + 0] = (_Float16)v.x;
            tile[tr][c0 + j * 4 + 1] = (_Float16)v.y;
            tile[tr][c0 + j * 4 + 2] = (_Float16)v.z;
            tile[tr][c0 + j * 4 + 3] = (_Float16)v.w;
        }
        __syncthreads();
        const int fr = tid >> 2;
        const int bb = (tid & 3) * 16;
        half8 o0, o1;
#pragma unroll
        for (int i = 0; i < 8; ++i) o0[i] = tile[bb + i][fr];
#pragma unroll
        for (int i = 0; i < 8; ++i) o1[i] = tile[bb + 8 + i][fr];
        _Float16* dst = xh + (size_t)(ft * 64 + fr) * BATCH + bt * 64 + bb;
        *(half8*)dst = o0;
        *(half8*)(dst + 8) = o1;
    } else {
        const int idx = (bid - 4352) * 256 + tid;   // 0..8191 = (f,s) pairs x2
        const int f = idx >> 5, s = (idx >> 1) & 15, hh = idx & 1;
        _Float16* dst = w1b1 + (size_t)(f * 16 + s) * 32 + hh * 8;
#pragma unroll
        for (int j = 0; j < 8; ++j) {
            const int k = 16 * s + kp32(hh, j);
            dst[j]      = (_Float16)W1[f * H1D + k];
            dst[16 + j] = (_Float16)b1[f * H1D + k];
        }
    }
}

// ---------------------------------------------------------------------------
// Main: 512 blocks (EXACTLY 2/CU, one residency round) x 4 waves (2/SIMD).
// Wave = 64 rows (2 m-tiles of 32) x 64 cols (2 n-tiles of 32) x 16 features.
// mfma_f32_32x32x16_f16: HALF the MFMA instructions of 16x16x32 at the same
// FLOPs, 15% faster pipe. A-frags recomputed in regs (kp32 map = w2f's map);
// B frags + w1/b1 double-buffered in regs; running 32-bit offsets; b2 folded
// into acc init. Barrier-free, LDS-free.
// ---------------------------------------------------------------------------
__global__ __launch_bounds__(256, 2) void coxnam_main(
    const _Float16* __restrict__ xh,  const _Float16* __restrict__ w1b1,
    const _Float16* __restrict__ w2f, const float* __restrict__ b2,
    const float* __restrict__ W3,     float* __restrict__ partial) {
    const int t    = threadIdx.x;
    const int w    = t >> 6;
    const int lane = t & 63;
    const int h = lane >> 5, c = lane & 31;     // k-half, row/col-in-32
    const int bid = blockIdx.x;                 // 0..511
    const int xcd = bid & 7;
    const int r_  = bid >> 3;                   // 0..63
    const int fsplit = (xcd << 1) | (r_ & 1);   // 0..15 (16 features each)
    const int u   = r_ >> 1;                    // 0..31
    const int ns  = u & 1, btg = u >> 1;        // btg 0..15
    const int b0  = (btg * 4 + w) * 64;         // 64 rows per wave
    const int f0  = fsplit * 16;

    f32x16 acc[2][2];            // 64 regs
    float  sacc[2][16];          // 32 regs
    half8  bfb[2][2];            // 16 regs
    half8  wvb[2], bvb[2];       // 16 regs
    _Float16 xs[2];
#pragma unroll
    for (int mt = 0; mt < 2; ++mt)
#pragma unroll
        for (int r = 0; r < 16; ++r) sacc[mt][r] = 0.f;

    // running offsets (element units)
    int off_b = f0 * 32768 + ns * 1024 + lane * 8;  // w2f: +2048 per k-step
    int off_w = f0 * 512 + h * 8;                   // w1b1: +32 per k-step
    int off_x = f0 * BATCH + b0 + c;                // xh:   +BATCH per feature
    int off_e = f0 * H2D + ns * 64 + c;             // b2/W3:+H2D per feature

    // prologue: k-step 0 -> ring 0
    bfb[0][0] = *(const half8*)(w2f + off_b);
    bfb[0][1] = *(const half8*)(w2f + off_b + 512);
    wvb[0] = *(const half8*)(w1b1 + off_w);
    bvb[0] = *(const half8*)(w1b1 + off_w + 16);
    off_b += 2048;
    off_w += 32;

    for (int fi = 0; fi < 16; ++fi) {
        // b2 folded into acc init
        {
            const float b2v0 = b2[off_e], b2v1 = b2[off_e + 32];
#pragma unroll
            for (int mt = 0; mt < 2; ++mt)
#pragma unroll
                for (int r = 0; r < 16; ++r) {
                    acc[mt][0][r] = b2v0;
                    acc[mt][1][r] = b2v1;
                }
        }
        xs[0] = xh[off_x];
        xs[1] = xh[off_x + 32];
#pragma unroll
        for (int s = 0; s < 16; ++s) {
            const int cur = s & 1, nxt = cur ^ 1;   // compile-time (unrolled)
            // prefetch next k-step (unguarded; final read lands in xh, unused)
            bfb[nxt][0] = *(const half8*)(w2f + off_b);
            bfb[nxt][1] = *(const half8*)(w2f + off_b + 512);
            wvb[nxt] = *(const half8*)(w1b1 + off_w);
            bvb[nxt] = *(const half8*)(w1b1 + off_w + 16);
            off_b += 2048;
            off_w += 32;
            // A-frag recompute (packed f16) + 4 MFMA
#pragma unroll
            for (int mt = 0; mt < 2; ++mt) {
                const half8 tt = xs[mt] * wvb[cur] + bvb[cur];
                const half8 af =
                    __builtin_elementwise_max(tt, (half8)(_Float16)0.0f);
                acc[mt][0] = __builtin_amdgcn_mfma_f32_32x32x16_f16(
                    af, bfb[cur][0], acc[mt][0], 0, 0, 0);
                acc[mt][1] = __builtin_amdgcn_mfma_f32_32x32x16_f16(
                    af, bfb[cur][1], acc[mt][1], 0, 0, 0);
            }
        }
        // ---- epilogue: relu(acc) . W3 -> sacc (b2 already inside acc) ----
        {
            const float w3v0 = W3[off_e], w3v1 = W3[off_e + 32];
#pragma unroll
            for (int mt = 0; mt < 2; ++mt)
#pragma unroll
                for (int r = 0; r < 16; ++r) {
                    const float va = fmaxf(acc[mt][0][r], 0.f);
                    const float vb = fmaxf(acc[mt][1][r], 0.f);
                    sacc[mt][r] = fmaf(va, w3v0, fmaf(vb, w3v1, sacc[mt][r]));
                }
        }
        off_x += BATCH;
        off_e += H2D;
    }

    // ---- reduce over the 32 n-cols (lanes within each half) ----
#pragma unroll
    for (int mt = 0; mt < 2; ++mt)
#pragma unroll
        for (int r = 0; r < 16; ++r) {
            float v = sacc[mt][r];
            v += __shfl_xor(v, 1, 32);
            v += __shfl_xor(v, 2, 32);
            v += __shfl_xor(v, 4, 32);
            v += __shfl_xor(v, 8, 32);
            v += __shfl_xor(v, 16, 32);
            sacc[mt][r] = v;
        }
    if (c == 0) {
        // C row map (verified m74/m101): row = (r&3) + 8*(r>>2) + 4h
        float* dst = partial + (size_t)(fsplit * 2 + ns) * BATCH + b0 + 4 * h;
#pragma unroll
        for (int mt = 0; mt < 2; ++mt)
#pragma unroll
            for (int r = 0; r < 16; ++r)
                dst[mt * 32 + (r & 3) + 8 * (r >> 2)] = sacc[mt][r];
    }
}

// ---------------------------------------------------------------------------
// Final reduction over 32 partials + sum of b3.
// ---------------------------------------------------------------------------
__global__ __launch_bounds__(256) void reduce_out(const float* __restrict__ partial,
                                                  const float* __restrict__ b3,
                                                  float* __restrict__ out) {
    const int b = blockIdx.x * 256 + threadIdx.x;
    float v = 0.f;
#pragma unroll
    for (int p = 0; p < NPART; ++p) v += partial[(size_t)p * BATCH + b];
    float sb3 = 0.f;
#pragma unroll 4
    for (int f4 = 0; f4 < FDIM; f4 += 4) {
        const float4 t = *(const float4*)(b3 + f4);
        sb3 += t.x + t.y + t.z + t.w;
    }
    out[b] = v + sb3;
}

extern "C" void kernel_launch(void* const* d_in, const int* in_sizes, int n_in,
                              void* d_out, int out_size, void* d_ws, size_t ws_size,
                              hipStream_t stream) {
    const float* x  = (const float*)d_in[0];
    const float* W1 = (const float*)d_in[1];
    const float* b1 = (const float*)d_in[2];
    const float* W2 = (const float*)d_in[3];
    const float* b2 = (const float*)d_in[4];
    const float* W3 = (const float*)d_in[5];
    const float* b3 = (const float*)d_in[6];

    _Float16* w2f  = (_Float16*)d_ws;
    _Float16* xh   = w2f + W2F_HALVES;
    _Float16* w1b1 = xh + XH_HALVES;
    float* partial = (float*)(w1b1 + W1B1_HALVES);
    const size_t need = (W2F_HALVES + XH_HALVES + W1B1_HALVES) * sizeof(_Float16) +
                        (size_t)NPART * BATCH * sizeof(float);
    if (ws_size < need) return;  // insufficient scratch; fail visibly

    prep_all<<<4384, 256, 0, stream>>>(x, W1, b1, W2, w2f, xh, w1b1);
    coxnam_main<<<512, 256, 0, stream>>>(xh, w1b1, w2f, b2, W3, partial);
    reduce_out<<<BATCH / 256, 256, 0, stream>>>(partial, b3, (float*)d_out);
}

// Round 14
// 81.979 us; speedup vs baseline: 2.8370x; 1.8452x over previous
//
#include <hip/hip_runtime.h>

#define FDIM  256
#define H1D   256
#define H2D   128
#define BATCH 4096
#define NPART 32

typedef _Float16 half8 __attribute__((ext_vector_type(8)));
typedef float    f32x4 __attribute__((ext_vector_type(4)));

#define W2F_HALVES  ((size_t)FDIM * H1D * H2D)   // 8388608  (16.78 MB)
#define XH_HALVES   ((size_t)FDIM * BATCH)       // 1048576  (2 MB)
#define W1B1_HALVES ((size_t)FDIM * 8 * 4 * 16)  // 131072   (0.25 MB)

// ---------------------------------------------------------------------------
// prep_all (identical to round-10 version):
//  [0,2048):   W2 -> w2f f16 B-fragments, k-perm kpat(g,j)=4g+j / 16+4g+(j-4)
//  [2048,2304): x (B,F) f32 -> xh (F,B) f16 transpose via LDS tile
//  [2304,2336): W1,b1 -> w1b1 packed per (f,s,g), SAME kpat sigma as w2f.
// ---------------------------------------------------------------------------
__global__ __launch_bounds__(256) void prep_all(
    const float* __restrict__ x,  const float* __restrict__ W1,
    const float* __restrict__ b1, const float* __restrict__ W2,
    _Float16* __restrict__ w2f, _Float16* __restrict__ xh,
    _Float16* __restrict__ w1b1) {
    __shared__ _Float16 tile[64][66];
    const int tid = threadIdx.x;
    const int bid = blockIdx.x;
    if (bid < 2048) {
        const int f = bid >> 3, s = bid & 7;
        const int lane = tid & 63, g = lane >> 4, ln = lane & 15;
        const int w = tid >> 6;
#pragma unroll
        for (int h = 0; h < 2; ++h) {
            const int tq = w * 2 + h;
            half8 v;
#pragma unroll
            for (int j = 0; j < 8; ++j) {
                const int k = s * 32 + 4 * g + (j < 4 ? j : 12 + j);
                v[j] = (_Float16)W2[(size_t)(f * H1D + k) * H2D + tq * 16 + ln];
            }
            *(half8*)(w2f + (((size_t)(f * 8 + s) * 8 + tq) * 64 + lane) * 8) = v;
        }
    } else if (bid < 2304) {
        const int idx = bid - 2048;
        const int bt = idx >> 2, ft = idx & 3;
        const int tr = tid >> 2;
        const int c0 = (tid & 3) * 16;
#pragma unroll
        for (int j = 0; j < 4; ++j) {
            const float4 v = *(const float4*)(
                x + (size_t)(bt * 64 + tr) * FDIM + ft * 64 + c0 + j * 4);
            tile[tr][c0 + j * 4 + 0] = (_Float16)v.x;
            tile[tr][c0 + j * 4 + 1] = (_Float16)v.y;
            tile[tr][c0 + j * 4 + 2] = (_Float16)v.z;
            tile[tr][c0 + j * 4 + 3] = (_Float16)v.w;
        }
        __syncthreads();
        const int fr = tid >> 2;
        const int bb = (tid & 3) * 16;
        half8 o0, o1;
#pragma unroll
        for (int i = 0; i < 8; ++i) o0[i] = tile[bb + i][fr];
#pragma unroll
        for (int i = 0; i < 8; ++i) o1[i] = tile[bb + 8 + i][fr];
        _Float16* dst = xh + (size_t)(ft * 64 + fr) * BATCH + bt * 64 + bb;
        *(half8*)dst = o0;
        *(half8*)(dst + 8) = o1;
    } else {
        const int idx = (bid - 2304) * 256 + tid;
        const int f = idx >> 5, s = (idx >> 2) & 7, g = idx & 3;
        const float4 wlo = *(const float4*)(W1 + f * H1D + s * 32 + 4 * g);
        const float4 whi = *(const float4*)(W1 + f * H1D + s * 32 + 16 + 4 * g);
        const float4 blo = *(const float4*)(b1 + f * H1D + s * 32 + 4 * g);
        const float4 bhi = *(const float4*)(b1 + f * H1D + s * 32 + 16 + 4 * g);
        half8 wv, bv;
        wv[0] = (_Float16)wlo.x; wv[1] = (_Float16)wlo.y;
        wv[2] = (_Float16)wlo.z; wv[3] = (_Float16)wlo.w;
        wv[4] = (_Float16)whi.x; wv[5] = (_Float16)whi.y;
        wv[6] = (_Float16)whi.z; wv[7] = (_Float16)whi.w;
        bv[0] = (_Float16)blo.x; bv[1] = (_Float16)blo.y;
        bv[2] = (_Float16)blo.z; bv[3] = (_Float16)blo.w;
        bv[4] = (_Float16)bhi.x; bv[5] = (_Float16)bhi.y;
        bv[6] = (_Float16)bhi.z; bv[7] = (_Float16)bhi.w;
        _Float16* dst = w1b1 + (size_t)((f * 8 + s) * 4 + g) * 16;
        *(half8*)dst = wv;
        *(half8*)(dst + 8) = bv;
    }
}

// ---------------------------------------------------------------------------
// Main: 512 blocks (2/CU) x 4 waves (2/SIMD). Waves share (fsplit, ns),
// own batch tiles. Per FEATURE (not per chunk): stage next feature's 32 KB
// B-slice into LDS via 8x global_load_lds per wave (issued at feature start,
// ~2500 cyc of MFMA cover), ONE barrier per feature. Chunks (BK=32) read
// B-frags from LDS via ds_read_b128 ring (separate pipe; L2 traffic 4x cut,
// guaranteed). A-frags recomputed in regs (half8 packed ops). w1b1 stays a
// global double-buffered ring (L1-hot). b2 folded into acc init. setprio
// wraps MFMA bursts.
// ---------------------------------------------------------------------------
__global__ __launch_bounds__(256, 2) void coxnam_main(
    const _Float16* __restrict__ xh,  const _Float16* __restrict__ w1b1,
    const _Float16* __restrict__ w2f, const float* __restrict__ b2,
    const float* __restrict__ W3,     float* __restrict__ partial) {
    __shared__ _Float16 lsh[2][16384];   // 2 x 32 KB feature B-slices

    const int t    = threadIdx.x;
    const int w    = t >> 6;
    const int lane = t & 63;
    const int g = lane >> 4, ln = lane & 15;
    const int bid = blockIdx.x;                 // 0..511
    const int xcd = bid & 7;
    const int r_  = bid >> 3;                   // 0..63
    const int fsplit = (xcd << 1) | (r_ & 1);   // 0..15 (16 features each)
    const int u   = r_ >> 1;                    // 0..31
    const int ns  = u & 1, btg = u >> 1;        // btg 0..15
    const int b0  = (btg * 4 + w) * 64;         // 64 rows per wave
    const int n0  = ns * 64, f0 = fsplit * 16;

    // stage feature f's (ns-half) B-slice: 8 pieces of 4 KB, 1 gll per piece
    auto stage = [&](int f, int buf) {
        const _Float16* src = w2f + (size_t)f * 32768 + ns * 2048 + t * 8;
#pragma unroll
        for (int i = 0; i < 8; ++i) {
            __builtin_amdgcn_global_load_lds(
                (const __attribute__((address_space(1))) unsigned int*)
                    (const void*)(src + i * 4096),
                (__attribute__((address_space(3))) unsigned int*)
                    (void*)&lsh[buf][i * 2048 + w * 512],
                16, 0, 0);
        }
    };

    f32x4 acc[4][4];
    float sacc[4][4];
    half8 bfb[2][4];
    half8 wvb[2], bvb[2];
    _Float16 xs[4];
#pragma unroll
    for (int mi = 0; mi < 4; ++mi)
#pragma unroll
        for (int r = 0; r < 4; ++r) sacc[mi][r] = 0.f;

    // running offsets
    int off_w = f0 * 512 + g * 16;              // w1b1: +64 per chunk
    int off_x = f0 * BATCH + b0 + ln;           // xh:   +BATCH per feature
    int off_e = f0 * H2D + n0 + ln;             // b2/W3:+H2D per feature

    // prologue: stage f0 into buf 0; first w1b1 chunk into ring 0
    stage(f0, 0);
    wvb[0] = *(const half8*)(w1b1 + off_w);
    bvb[0] = *(const half8*)(w1b1 + off_w + 8);
    off_w += 64;
    __syncthreads();

    for (int fi = 0; fi < 16; ++fi) {
        const int buf = fi & 1;
        // b2 -> acc init; x scalars for this feature
        {
            float b2v[4];
#pragma unroll
            for (int nt = 0; nt < 4; ++nt) b2v[nt] = b2[off_e + nt * 16];
#pragma unroll
            for (int mi = 0; mi < 4; ++mi)
#pragma unroll
                for (int nt = 0; nt < 4; ++nt)
                    acc[mi][nt] = (f32x4){b2v[nt], b2v[nt], b2v[nt], b2v[nt]};
        }
#pragma unroll
        for (int mi = 0; mi < 4; ++mi) xs[mi] = xh[off_x + mi * 16];
        // chunk 0 B-frags from LDS; then issue next feature's stage
        const _Float16* lbase = &lsh[buf][0] + lane * 8;
#pragma unroll
        for (int nt = 0; nt < 4; ++nt)
            bfb[0][nt] = *(const half8*)(lbase + nt * 512);
        if (fi < 15) stage(f0 + fi + 1, buf ^ 1);

#pragma unroll
        for (int s = 0; s < 8; ++s) {
            const int cur = s & 1, nxt = cur ^ 1;   // compile-time
            // prefetch next chunk's B-frags from LDS
            if (s < 7) {
#pragma unroll
                for (int nt = 0; nt < 4; ++nt)
                    bfb[nxt][nt] =
                        *(const half8*)(lbase + (s + 1) * 2048 + nt * 512);
            }
            // w1b1 ring prefetch (global, L1-hot); unguarded tail reads are
            // harmless (land in xh region of d_ws, unused)
            wvb[nxt] = *(const half8*)(w1b1 + off_w);
            bvb[nxt] = *(const half8*)(w1b1 + off_w + 8);
            off_w += 64;
            // A-frag recompute (packed f16) + 16-MFMA burst
            __builtin_amdgcn_s_setprio(1);
#pragma unroll
            for (int mi = 0; mi < 4; ++mi) {
                const half8 tt = xs[mi] * wvb[cur] + bvb[cur];
                const half8 af =
                    __builtin_elementwise_max(tt, (half8)(_Float16)0.0f);
#pragma unroll
                for (int nt = 0; nt < 4; ++nt)
                    acc[mi][nt] = __builtin_amdgcn_mfma_f32_16x16x32_f16(
                        af, bfb[cur][nt], acc[mi][nt], 0, 0, 0);
            }
            __builtin_amdgcn_s_setprio(0);
        }
        // ---- epilogue: relu(acc) . W3 -> sacc ----
        {
            float w3v[4];
#pragma unroll
            for (int nt = 0; nt < 4; ++nt) w3v[nt] = W3[off_e + nt * 16];
#pragma unroll
            for (int mi = 0; mi < 4; ++mi)
#pragma unroll
                for (int nt = 0; nt < 4; ++nt)
#pragma unroll
                    for (int r = 0; r < 4; ++r) {
                        const float v = fmaxf(acc[mi][nt][r], 0.f);
                        sacc[mi][r] = fmaf(v, w3v[nt], sacc[mi][r]);
                    }
        }
        off_x += BATCH;
        off_e += H2D;
        __syncthreads();   // next feature's stage complete; buf swap safe
    }

    // ---- reduce over the 16 n-lanes ----
#pragma unroll
    for (int mi = 0; mi < 4; ++mi)
#pragma unroll
        for (int r = 0; r < 4; ++r) {
            float v = sacc[mi][r];
            v += __shfl_xor(v, 1, 16);
            v += __shfl_xor(v, 2, 16);
            v += __shfl_xor(v, 4, 16);
            v += __shfl_xor(v, 8, 16);
            sacc[mi][r] = v;
        }
    if (ln == 0) {
        float* dst = partial + (size_t)(fsplit * 2 + ns) * BATCH + b0;
#pragma unroll
        for (int mi = 0; mi < 4; ++mi) {
            f32x4 o = {sacc[mi][0], sacc[mi][1], sacc[mi][2], sacc[mi][3]};
            *(f32x4*)(dst + mi * 16 + g * 4) = o;
        }
    }
}

// ---------------------------------------------------------------------------
// Final reduction over 32 partials + sum of b3.
// ---------------------------------------------------------------------------
__global__ __launch_bounds__(256) void reduce_out(const float* __restrict__ partial,
                                                  const float* __restrict__ b3,
                                                  float* __restrict__ out) {
    const int b = blockIdx.x * 256 + threadIdx.x;
    float v = 0.f;
#pragma unroll
    for (int p = 0; p < NPART; ++p) v += partial[(size_t)p * BATCH + b];
    float sb3 = 0.f;
#pragma unroll 4
    for (int f4 = 0; f4 < FDIM; f4 += 4) {
        const float4 t = *(const float4*)(b3 + f4);
        sb3 += t.x + t.y + t.z + t.w;
    }
    out[b] = v + sb3;
}

extern "C" void kernel_launch(void* const* d_in, const int* in_sizes, int n_in,
                              void* d_out, int out_size, void* d_ws, size_t ws_size,
                              hipStream_t stream) {
    const float* x  = (const float*)d_in[0];
    const float* W1 = (const float*)d_in[1];
    const float* b1 = (const float*)d_in[2];
    const float* W2 = (const float*)d_in[3];
    const float* b2 = (const float*)d_in[4];
    const float* W3 = (const float*)d_in[5];
    const float* b3 = (const float*)d_in[6];

    _Float16* w2f  = (_Float16*)d_ws;
    _Float16* xh   = w2f + W2F_HALVES;
    _Float16* w1b1 = xh + XH_HALVES;
    float* partial = (float*)(w1b1 + W1B1_HALVES);
    const size_t need = (W2F_HALVES + XH_HALVES + W1B1_HALVES) * sizeof(_Float16) +
                        (size_t)NPART * BATCH * sizeof(float);
    if (ws_size < need) return;  // insufficient scratch; fail visibly

    prep_all<<<2336, 256, 0, stream>>>(x, W1, b1, W2, w2f, xh, w1b1);
    coxnam_main<<<512, 256, 0, stream>>>(xh, w1b1, w2f, b2, W3, partial);
    reduce_out<<<BATCH / 256, 256, 0, stream>>>(partial, b3, (float*)d_out);
}